// Round 1
// baseline (4127.631 us; speedup 1.0000x reference)
//
#include <hip/hip_runtime.h>
#include <math.h>

// Problem constants
#define DDIM   256            // superoperator dimension
#define NTS    128            // timesteps
#define PLANE  65536          // 256*256 floats per (re or im) plane
#define SLOT   131072         // re+im planes per matrix slot (floats)
#define DT_C   0.02f

// ---------------------------------------------------------------------------
// build_B: B_k = (DT/2^6) * (dyn + sum_j cr[k,j]*Gp_j + i*sum_j ci[k,j]*Gm_j)
// also writes Rinit = I + B/12   (the k=12 Horner step, since R starts = I)
// ---------------------------------------------------------------------------
__global__ __launch_bounds__(256)
void build_B_kernel(const float* __restrict__ cr, const float* __restrict__ ci,
                    const float* __restrict__ dre, const float* __restrict__ dimg,
                    const float* __restrict__ gre, const float* __restrict__ gim,
                    float* __restrict__ Bm, float* __restrict__ Rini, int ts0)
{
    const int ts  = blockIdx.y;
    const int k   = ts0 + ts;
    const int idx = blockIdx.x * blockDim.x + threadIdx.x;   // 0..PLANE-1

    const float c0 = cr[2*k],  c1 = cr[2*k+1];
    const float e0 = ci[2*k],  e1 = ci[2*k+1];

    // ctrl_gen layout: [j][s][256][256]
    const float gr00 = gre[0*PLANE + idx];
    const float gr01 = gre[1*PLANE + idx];
    const float gr10 = gre[2*PLANE + idx];
    const float gr11 = gre[3*PLANE + idx];
    const float gi00 = gim[0*PLANE + idx];
    const float gi01 = gim[1*PLANE + idx];
    const float gi10 = gim[2*PLANE + idx];
    const float gi11 = gim[3*PLANE + idx];

    // A = dyn + sum cr_j*(G0+G1) + i*sum ci_j*(G0-G1)
    const float are = dre[idx]  + c0*(gr00+gr01) + c1*(gr10+gr11)
                                - e0*(gi00-gi01) - e1*(gi10-gi11);
    const float aim = dimg[idx] + c0*(gi00+gi01) + c1*(gi10+gi11)
                                + e0*(gr00-gr01) + e1*(gr10-gr11);

    const float coef = DT_C / 64.0f;   // DT / 2^SQUARINGS
    const float br = coef * are;
    const float bi = coef * aim;

    float* B = Bm + (size_t)ts * SLOT;
    B[idx]         = br;
    B[PLANE + idx] = bi;

    const int row = idx >> 8, col = idx & 255;
    const float dg = (row == col) ? 1.0f : 0.0f;
    float* R = Rini + (size_t)ts * SLOT;
    R[idx]         = dg + br * (1.0f/12.0f);
    R[PLANE + idx] =      bi * (1.0f/12.0f);
}

// ---------------------------------------------------------------------------
// Batched complex GEMM: C = alpha*(A@B) + addI*I    (256x256x256 per batch)
// Each matrix slot = [re plane][im plane], SLOT floats.
// Operand address: base + (z*scale + off)*SLOT
// Block: 256 threads -> 64x64 output tile, 4x4 per thread (re+im accums).
// ---------------------------------------------------------------------------
__global__ __launch_bounds__(256)
void cgemm_kernel(const float* __restrict__ Ab, const float* __restrict__ Bb,
                  float* __restrict__ Cb,
                  int aS, int aO, int bS, int bO, int cS, int cO,
                  float alpha, int addI)
{
    __shared__ float Asr[16][64];   // [k][m] (transposed on stage)
    __shared__ float Asi[16][64];
    __shared__ float Bsr[16][64];   // [k][n]
    __shared__ float Bsi[16][64];

    const int z = blockIdx.z;
    const float* __restrict__ Ar = Ab + (size_t)(z*aS + aO) * SLOT;
    const float* __restrict__ Ai = Ar + PLANE;
    const float* __restrict__ Br = Bb + (size_t)(z*bS + bO) * SLOT;
    const float* __restrict__ Bi = Br + PLANE;
    float* Cr = Cb + (size_t)(z*cS + cO) * SLOT;
    float* Ci = Cr + PLANE;

    const int t  = threadIdx.x;
    const int tx = t & 15;          // 0..15 col group
    const int ty = t >> 4;          // 0..15 row group
    const int bm = blockIdx.y * 64;
    const int bn = blockIdx.x * 64;

    // staging indices
    const int lr = t >> 2;          // 0..63 A-tile row
    const int lq = t & 3;           // 0..3  A-tile k-quad
    const int kr = t >> 4;          // 0..15 B-tile k row
    const int nc = (t & 15) * 4;    // B-tile col

    float accR[4][4] = {{0.f}}, accI[4][4] = {{0.f}};

    for (int k0 = 0; k0 < DDIM; k0 += 16) {
        __syncthreads();
        const float4 avr = *(const float4*)&Ar[(bm+lr)*DDIM + k0 + lq*4];
        const float4 avi = *(const float4*)&Ai[(bm+lr)*DDIM + k0 + lq*4];
        const float4 bvr = *(const float4*)&Br[(k0+kr)*DDIM + bn + nc];
        const float4 bvi = *(const float4*)&Bi[(k0+kr)*DDIM + bn + nc];
        Asr[lq*4+0][lr] = avr.x; Asr[lq*4+1][lr] = avr.y;
        Asr[lq*4+2][lr] = avr.z; Asr[lq*4+3][lr] = avr.w;
        Asi[lq*4+0][lr] = avi.x; Asi[lq*4+1][lr] = avi.y;
        Asi[lq*4+2][lr] = avi.z; Asi[lq*4+3][lr] = avi.w;
        *(float4*)&Bsr[kr][nc] = bvr;
        *(float4*)&Bsi[kr][nc] = bvi;
        __syncthreads();

        #pragma unroll
        for (int kk = 0; kk < 16; ++kk) {
            const float4 a4r = *(const float4*)&Asr[kk][ty*4];
            const float4 a4i = *(const float4*)&Asi[kk][ty*4];
            const float4 b4r = *(const float4*)&Bsr[kk][tx*4];
            const float4 b4i = *(const float4*)&Bsi[kk][tx*4];
            const float arr[4] = {a4r.x, a4r.y, a4r.z, a4r.w};
            const float aii[4] = {a4i.x, a4i.y, a4i.z, a4i.w};
            const float brr[4] = {b4r.x, b4r.y, b4r.z, b4r.w};
            const float bii[4] = {b4i.x, b4i.y, b4i.z, b4i.w};
            #pragma unroll
            for (int i = 0; i < 4; ++i)
                #pragma unroll
                for (int j = 0; j < 4; ++j) {
                    accR[i][j] += arr[i]*brr[j];
                    accR[i][j] -= aii[i]*bii[j];
                    accI[i][j] += arr[i]*bii[j];
                    accI[i][j] += aii[i]*brr[j];
                }
        }
    }

    #pragma unroll
    for (int i = 0; i < 4; ++i) {
        const int m  = bm + ty*4 + i;
        const int n0 = bn + tx*4;
        float oR[4], oI[4];
        #pragma unroll
        for (int j = 0; j < 4; ++j) {
            oR[j] = alpha * accR[i][j];
            oI[j] = alpha * accI[i][j];
            if (addI && m == n0 + j) oR[j] += 1.0f;
        }
        *(float4*)&Cr[m*DDIM + n0] = make_float4(oR[0], oR[1], oR[2], oR[3]);
        *(float4*)&Ci[m*DDIM + n0] = make_float4(oI[0], oI[1], oI[2], oI[3]);
    }
}

// ---------------------------------------------------------------------------
// final: v = Ptot @ s0 ; c = sum(v[diag]) ; sT = v/c ; fid = ||sT - tgt||_F
// ---------------------------------------------------------------------------
__global__ __launch_bounds__(256)
void final_kernel(const float* __restrict__ Pt,
                  const float* __restrict__ s0r, const float* __restrict__ s0i,
                  const float* __restrict__ tgr, const float* __restrict__ tgi,
                  float* __restrict__ out, int outSize)
{
    __shared__ float sr[DDIM], si[DDIM], vr[DDIM], vi[DDIM], red[DDIM];
    __shared__ float cR, cI;
    const int t = threadIdx.x;
    sr[t] = s0r[t];
    si[t] = s0i[t];
    __syncthreads();

    const float* Pr = Pt;
    const float* Pi = Pt + PLANE;
    float ar = 0.f, ai = 0.f;
    for (int k = 0; k < DDIM; ++k) {
        const float pr = Pr[t*DDIM + k], pi = Pi[t*DDIM + k];
        ar += pr*sr[k] - pi*si[k];
        ai += pr*si[k] + pi*sr[k];
    }
    vr[t] = ar; vi[t] = ai;
    __syncthreads();

    if (t == 0) {
        float xr = 0.f, xi = 0.f;
        for (int i = 0; i < 16; ++i) { xr += vr[i*17]; xi += vi[i*17]; }
        cR = xr; cI = xi;
    }
    __syncthreads();

    const float den = cR*cR + cI*cI;
    const float str = (ar*cR + ai*cI) / den;
    const float sti = (ai*cR - ar*cI) / den;

    const float dr = str - tgr[t];
    const float di = sti - tgi[t];
    red[t] = dr*dr + di*di;
    __syncthreads();
    for (int s = 128; s > 0; s >>= 1) {
        if (t < s) red[t] += red[t + s];
        __syncthreads();
    }
    const float fid = sqrtf(red[0]);

    if (outSize >= 2*DDIM + 1) {
        out[2*t]   = str;
        out[2*t+1] = sti;
        if (t == 0) out[2*DDIM] = fid;
    } else if (outSize == 2*DDIM) {
        out[2*t]   = str;
        out[2*t+1] = sti;
    } else {
        out[t] = str;
        if (t == 0 && outSize > DDIM) out[DDIM] = fid;
    }
}

// ---------------------------------------------------------------------------
extern "C" void kernel_launch(void* const* d_in, const int* in_sizes, int n_in,
                              void* d_out, int out_size, void* d_ws, size_t ws_size,
                              hipStream_t stream)
{
    (void)in_sizes; (void)n_in;
    const float* cr   = (const float*)d_in[0];
    const float* ci   = (const float*)d_in[1];
    const float* dre  = (const float*)d_in[2];
    const float* dimg = (const float*)d_in[3];
    const float* gre  = (const float*)d_in[4];
    const float* gim  = (const float*)d_in[5];
    const float* s0r  = (const float*)d_in[6];
    const float* s0i  = (const float*)d_in[7];
    const float* tgr  = (const float*)d_in[8];
    const float* tgi  = (const float*)d_in[9];

    float* ws = (float*)d_ws;
    const size_t MB = 1u << 20;

    // Workspace layout:
    //   P:   128 slots (64MB) -- propagators / tree ping
    //   full mode (ws >= 192MB): Bm 128 slots, Ralt 128 slots, tree temp = Ralt
    //   chunk mode: T 64 slots (32MB), Bm C slots, Ralt C slots
    float* P = ws;
    float* T; float* BmB; float* RaB; int C;
    if (ws_size >= 192 * MB) {
        BmB = ws + (size_t)128 * SLOT;
        RaB = BmB + (size_t)128 * SLOT;
        T   = RaB;
        C = 128;
    } else {
        T   = ws + (size_t)128 * SLOT;
        BmB = T + (size_t)64 * SLOT;
        long avail = (long)ws_size - (long)(96 * MB);
        C = (int)(avail / (long)MB);
        if (C < 1) C = 1;
        if (C > 128) C = 128;
        RaB = BmB + (size_t)C * SLOT;
    }

    // ---- expm phase: per chunk, 1 build + 11 Taylor + 6 squarings ----
    for (int ts0 = 0; ts0 < NTS; ts0 += C) {
        int nb = NTS - ts0; if (nb > C) nb = C;
        build_B_kernel<<<dim3(PLANE/256, nb), 256, 0, stream>>>(
            cr, ci, dre, dimg, gre, gim, BmB, RaB, ts0);

        float* curp = RaB;                       // holds I + B/12 (k=12 step)
        float* nxtp = P + (size_t)ts0 * SLOT;    // chunk's props slots
        for (int k = 11; k >= 1; --k) {          // R = I + (B@R)/k
            cgemm_kernel<<<dim3(4,4,nb), 256, 0, stream>>>(
                BmB, curp, nxtp, 1,0, 1,0, 1,0, 1.0f/(float)k, 1);
            float* tmp = curp; curp = nxtp; nxtp = tmp;
        }
        for (int q = 0; q < 6; ++q) {            // R = R @ R
            cgemm_kernel<<<dim3(4,4,nb), 256, 0, stream>>>(
                curp, curp, nxtp, 1,0, 1,0, 1,0, 1.0f, 0);
            float* tmp = curp; curp = nxtp; nxtp = tmp;
        }
        // 17 writes starting into P-slot => final propagator lands in P-slot.
    }

    // ---- product tree: Ptot = P127 @ ... @ P0  (normalization telescopes) ----
    const float* srcp = P;
    float* dstp = T;
    int n = NTS;
    while (n > 1) {
        cgemm_kernel<<<dim3(4,4,n/2), 256, 0, stream>>>(
            (const float*)srcp, (const float*)srcp, dstp,
            2,1, 2,0, 1,0, 1.0f, 0);             // Q_j = P_{2j+1} @ P_{2j}
        float* tmp = (float*)srcp; srcp = dstp; dstp = tmp;
        n >>= 1;
    }

    // ---- apply to s0, normalize once, fid err ----
    final_kernel<<<1, 256, 0, stream>>>(srcp, s0r, s0i, tgr, tgi,
                                        (float*)d_out, out_size);
}

// Round 2
// 1090.009 us; speedup vs baseline: 3.7868x; 3.7868x over previous
//
#include <hip/hip_runtime.h>
#include <math.h>

#define DD    256
#define PLQ   65536           // plane elems (u16) = 256*256
#define SLOTB 131072          // complex slot elems (u16): re plane + im plane
#define NTS   128
#define DT_C  0.02f

typedef unsigned short u16;
typedef unsigned int   u32;
typedef __attribute__((ext_vector_type(8))) short s16x8;
typedef __attribute__((ext_vector_type(4))) float f32x4;

typedef __attribute__((address_space(1))) const unsigned int GU32;
typedef __attribute__((address_space(3))) unsigned int LU32;

__device__ __forceinline__ u32 swz(u32 off) {       // 16B-chunk XOR swizzle (involution)
    return off ^ (((off >> 7) & 3u) << 4);
}
__device__ __forceinline__ u16 f2bf(float f) {
    u32 u = __float_as_uint(f);
    return (u16)((u + 0x7FFFu + ((u >> 16) & 1u)) >> 16);
}
__device__ __forceinline__ float bf2f(u16 h) {
    return __uint_as_float(((u32)h) << 16);
}
__device__ __forceinline__ void gll16(const u16* g, char* ldsBase, u32 ldsByteOff) {
    u32 off = (u32)__builtin_amdgcn_readfirstlane((int)ldsByteOff);
    __builtin_amdgcn_global_load_lds((GU32*)g, (LU32*)(ldsBase + off), 16, 0, 0);
}

// ---------------------------------------------------------------------------
// build: Bm = (DT/64)*A_ts  (bf16, N-layout) ; E12 = Bm/12 (bf16, N-layout)
// ---------------------------------------------------------------------------
__global__ __launch_bounds__(256)
void build_kernel(const float* __restrict__ cr, const float* __restrict__ ci,
                  const float* __restrict__ dre, const float* __restrict__ dimg,
                  const float* __restrict__ gre, const float* __restrict__ gim,
                  u16* __restrict__ BmN, u16* __restrict__ E12N, int ts0)
{
    const int ts  = blockIdx.y;
    const int k   = ts0 + ts;
    const int idx = blockIdx.x * 256 + threadIdx.x;

    const float c0 = cr[2*k], c1 = cr[2*k+1];
    const float e0 = ci[2*k], e1 = ci[2*k+1];

    const float gr00 = gre[0*PLQ + idx], gr01 = gre[1*PLQ + idx];
    const float gr10 = gre[2*PLQ + idx], gr11 = gre[3*PLQ + idx];
    const float gi00 = gim[0*PLQ + idx], gi01 = gim[1*PLQ + idx];
    const float gi10 = gim[2*PLQ + idx], gi11 = gim[3*PLQ + idx];

    const float are = dre[idx]  + c0*(gr00+gr01) + c1*(gr10+gr11)
                                - e0*(gi00-gi01) - e1*(gi10-gi11);
    const float aim = dimg[idx] + c0*(gi00+gi01) + c1*(gi10+gi11)
                                + e0*(gr00-gr01) + e1*(gr10-gr11);

    const float coef = DT_C / 64.0f;
    const float br = coef * are, bi = coef * aim;

    u16* B = BmN + (size_t)ts * SLOTB;
    B[idx]       = f2bf(br);
    B[PLQ + idx] = f2bf(bi);
    u16* E = E12N + (size_t)ts * SLOTB;
    E[idx]       = f2bf(br * (1.0f/12.0f));
    E[PLQ + idx] = f2bf(bi * (1.0f/12.0f));
}

// ---------------------------------------------------------------------------
// Batched complex bf16 MFMA GEMM in deviation form:
//   out = alpha*(A@B) + b1*X1 + b2*X2      (elementwise adds of X at coords)
// A read from N-layout (row-major [m][k]).  B: TRB=0 -> T-layout global via
// global_load_lds; TRB=1 -> N-layout global, scatter-transposed into LDS.
// Writes outN (N-layout) and/or outT (T-layout); either may be null.
// Tile 64x64, 4 waves, BK=32, mfma_f32_16x16x32_bf16.
// ---------------------------------------------------------------------------
template<int TRB>
__global__ __launch_bounds__(256)
void cgemm(const u16* __restrict__ Ab, const u16* __restrict__ Bb,
           u16* __restrict__ outN, u16* __restrict__ outT,
           const u16* __restrict__ X1b, const u16* __restrict__ X2b,
           float alpha, float b1, float b2,
           int aS, int aO, int bS, int bO, int cS, int cO,
           int x1S, int x1O, int x2S, int x2O)
{
    __shared__ char lds[16384];   // Are[64][32] | Aim | Bre[64][32](n-major) | Bim

    const int z = blockIdx.z;
    const u16* __restrict__ A = Ab + (size_t)(z*aS + aO) * SLOTB;
    const u16* __restrict__ B = Bb + (size_t)(z*bS + bO) * SLOTB;

    const int t  = threadIdx.x;
    const int bn = blockIdx.x * 64;
    const int bm = blockIdx.y * 64;

    // fast-path staging source mapping: dest chunk D=t*16 -> logical L=swz(D)
    const u32 D  = (u32)t * 16u;
    const u32 L  = swz(D);
    const int sr = (int)(L >> 6);          // tile row 0..63
    const int sk = (int)((L & 63u) >> 1);  // k elem offset 0..31 (16B aligned)
    const u32 wvoff = ((u32)(t >> 6)) * 1024u;  // wave-uniform LDS base

    // TRB staging mapping
    const int kRow = t >> 3;               // 0..31
    const int nCh  = t & 7;                // 0..7 -> n0 = nCh*8

    const int wv = t >> 6, ln = t & 63;
    const int wr = wv >> 1, wc = wv & 1;   // wave tile origin (wr*32, wc*32)
    const int lg = ln >> 4, lc = ln & 15;  // k-group, col

    f32x4 accR[2][2], accI[2][2];
    #pragma unroll
    for (int i = 0; i < 2; ++i)
        #pragma unroll
        for (int j = 0; j < 2; ++j) {
            accR[i][j] = (f32x4){0.f,0.f,0.f,0.f};
            accI[i][j] = (f32x4){0.f,0.f,0.f,0.f};
        }

    for (int k0 = 0; k0 < DD; k0 += 32) {
        __syncthreads();
        // ---- stage A (always gll from N-layout) ----
        gll16(A +        (size_t)(bm + sr)*DD + k0 + sk, lds,     0u + wvoff);
        gll16(A + PLQ +  (size_t)(bm + sr)*DD + k0 + sk, lds,  4096u + wvoff);
        if (TRB == 0) {
            // ---- stage B from T-layout ----
            gll16(B +       (size_t)(bn + sr)*DD + k0 + sk, lds,  8192u + wvoff);
            gll16(B + PLQ + (size_t)(bn + sr)*DD + k0 + sk, lds, 12288u + wvoff);
        } else {
            // ---- stage B from N-layout [k][n]: scatter-transpose ----
            const s16x8 vr = *(const s16x8*)(B +       (size_t)(k0 + kRow)*DD + bn + nCh*8);
            const s16x8 vi = *(const s16x8*)(B + PLQ + (size_t)(k0 + kRow)*DD + bn + nCh*8);
            #pragma unroll
            for (int e = 0; e < 8; ++e) {
                const u32 off = swz((u32)(nCh*8 + e)*64u + (u32)kRow*2u);
                *(u16*)(lds +  8192 + off) = (u16)vr[e];
                *(u16*)(lds + 12288 + off) = (u16)vi[e];
            }
        }
        __syncthreads();

        // ---- fragments ----
        s16x8 ar[2], ai[2], aiN[2], br[2], bi[2];
        #pragma unroll
        for (int fm = 0; fm < 2; ++fm) {
            const u32 so = swz((u32)(wr*32 + fm*16 + lc)*64u + (u32)lg*16u);
            ar[fm]  = *(const s16x8*)(lds + so);
            ai[fm]  = *(const s16x8*)(lds + 4096 + so);
            aiN[fm] = ai[fm] ^ (short)0x8000u;       // negated imag
        }
        #pragma unroll
        for (int fn = 0; fn < 2; ++fn) {
            const u32 so = swz((u32)(wc*32 + fn*16 + lc)*64u + (u32)lg*16u);
            br[fn] = *(const s16x8*)(lds +  8192 + so);
            bi[fn] = *(const s16x8*)(lds + 12288 + so);
        }
        // ---- MFMA ----
        #pragma unroll
        for (int fm = 0; fm < 2; ++fm)
            #pragma unroll
            for (int fn = 0; fn < 2; ++fn) {
                accR[fm][fn] = __builtin_amdgcn_mfma_f32_16x16x32_bf16(ar[fm],  br[fn], accR[fm][fn], 0, 0, 0);
                accR[fm][fn] = __builtin_amdgcn_mfma_f32_16x16x32_bf16(aiN[fm], bi[fn], accR[fm][fn], 0, 0, 0);
                accI[fm][fn] = __builtin_amdgcn_mfma_f32_16x16x32_bf16(ar[fm],  bi[fn], accI[fm][fn], 0, 0, 0);
                accI[fm][fn] = __builtin_amdgcn_mfma_f32_16x16x32_bf16(ai[fm],  br[fn], accI[fm][fn], 0, 0, 0);
            }
    }

    // ---- epilogue ----
    u16* oN = outN ? outN + (size_t)(z*cS + cO) * SLOTB : nullptr;
    u16* oT = outT ? outT + (size_t)(z*cS + cO) * SLOTB : nullptr;
    const u16* x1 = X1b ? X1b + (size_t)(z*x1S + x1O) * SLOTB : nullptr;
    const u16* x2 = X2b ? X2b + (size_t)(z*x2S + x2O) * SLOTB : nullptr;

    #pragma unroll
    for (int fm = 0; fm < 2; ++fm)
        #pragma unroll
        for (int fn = 0; fn < 2; ++fn) {
            const int rb = bm + wr*32 + fm*16 + lg*4;
            const int c  = bn + wc*32 + fn*16 + lc;
            u16 tR[4], tI[4];
            #pragma unroll
            for (int j = 0; j < 4; ++j) {
                const int r = rb + j;
                float vR = alpha * accR[fm][fn][j];
                float vI = alpha * accI[fm][fn][j];
                if (x1) { vR += b1 * bf2f(x1[(size_t)r*DD + c]);
                          vI += b1 * bf2f(x1[PLQ + (size_t)r*DD + c]); }
                if (x2) { vR += b2 * bf2f(x2[(size_t)r*DD + c]);
                          vI += b2 * bf2f(x2[PLQ + (size_t)r*DD + c]); }
                const u16 hR = f2bf(vR), hI = f2bf(vI);
                if (oN) { oN[(size_t)r*DD + c] = hR; oN[PLQ + (size_t)r*DD + c] = hI; }
                tR[j] = hR; tI[j] = hI;
            }
            if (oT) {
                *(ushort4*)(oT + (size_t)c*DD + rb)       = make_ushort4(tR[0], tR[1], tR[2], tR[3]);
                *(ushort4*)(oT + PLQ + (size_t)c*DD + rb) = make_ushort4(tI[0], tI[1], tI[2], tI[3]);
            }
        }
}

// ---------------------------------------------------------------------------
// final: v = s0 + Etot@s0 ; c = sum(v[diag]) ; sT = v/c ; fid = ||sT-tgt||_F
// ---------------------------------------------------------------------------
__global__ __launch_bounds__(256)
void final_kernel(const u16* __restrict__ Et,
                  const float* __restrict__ s0r, const float* __restrict__ s0i,
                  const float* __restrict__ tgr, const float* __restrict__ tgi,
                  float* __restrict__ out, int outSize)
{
    __shared__ float sr[DD], si[DD], vr[DD], vi[DD], red[DD];
    __shared__ float cR, cI;
    const int t = threadIdx.x;
    sr[t] = s0r[t];
    si[t] = s0i[t];
    __syncthreads();

    const u16* Er = Et;
    const u16* Ei = Et + PLQ;
    float ar = sr[t], ai = si[t];
    for (int k = 0; k < DD; ++k) {
        const float pr = bf2f(Er[(size_t)t*DD + k]);
        const float pi = bf2f(Ei[(size_t)t*DD + k]);
        ar += pr*sr[k] - pi*si[k];
        ai += pr*si[k] + pi*sr[k];
    }
    vr[t] = ar; vi[t] = ai;
    __syncthreads();

    if (t == 0) {
        float xr = 0.f, xi = 0.f;
        for (int i = 0; i < 16; ++i) { xr += vr[i*17]; xi += vi[i*17]; }
        cR = xr; cI = xi;
    }
    __syncthreads();

    const float den = cR*cR + cI*cI;
    const float str = (ar*cR + ai*cI) / den;
    const float sti = (ai*cR - ar*cI) / den;

    const float dr = str - tgr[t];
    const float di = sti - tgi[t];
    red[t] = dr*dr + di*di;
    __syncthreads();
    for (int s = 128; s > 0; s >>= 1) {
        if (t < s) red[t] += red[t + s];
        __syncthreads();
    }
    const float fid = sqrtf(red[0]);

    if (outSize >= 2*DD + 1) {
        out[2*t] = str; out[2*t+1] = sti;
        if (t == 0) out[2*DD] = fid;
    } else if (outSize == 2*DD) {
        out[2*t] = str; out[2*t+1] = sti;
    } else {
        out[t] = str;
        if (t == 0 && outSize > DD) out[DD] = fid;
    }
}

// ---------------------------------------------------------------------------
extern "C" void kernel_launch(void* const* d_in, const int* in_sizes, int n_in,
                              void* d_out, int out_size, void* d_ws, size_t ws_size,
                              hipStream_t stream)
{
    (void)in_sizes; (void)n_in;
    const float* cr   = (const float*)d_in[0];
    const float* ci   = (const float*)d_in[1];
    const float* dre  = (const float*)d_in[2];
    const float* dimg = (const float*)d_in[3];
    const float* gre  = (const float*)d_in[4];
    const float* gim  = (const float*)d_in[5];
    const float* s0r  = (const float*)d_in[6];
    const float* s0i  = (const float*)d_in[7];
    const float* tgr  = (const float*)d_in[8];
    const float* tgi  = (const float*)d_in[9];

    u16* ws = (u16*)d_ws;
    u16* P  = ws;                          // 128 N-slots: final propagator deviations E
    u16* CB = ws + 128L * SLOTB;           // chunk region (also tree ping buffer)

    long availU = (long)(ws_size / 2) - 128L * SLOTB;
    int C = (int)(availU / (5L * SLOTB));
    if (C > NTS) C = NTS;
    if (C < 13) C = 13;                    // tree ping (64 slots) must fit in 5C

    for (int ts0 = 0; ts0 < NTS; ts0 += C) {
        int nb = NTS - ts0; if (nb > C) nb = C;
        u16* BmN = CB;
        u16* D1N = CB + 1L*C*SLOTB;
        u16* D1T = CB + 2L*C*SLOTB;
        u16* D2N = CB + 3L*C*SLOTB;
        u16* D2T = CB + 4L*C*SLOTB;

        build_kernel<<<dim3(PLQ/256, nb), 256, 0, stream>>>(
            cr, ci, dre, dimg, gre, gim, BmN, D1N, ts0);

        const dim3 grid(4, 4, nb);
        // Taylor k=11 (right operand from N-layout via scatter-transpose)
        cgemm<1><<<grid, 256, 0, stream>>>(BmN, D1N, nullptr, D2T, BmN, nullptr,
            1.0f/11.f, 1.0f/11.f, 0.f, 1,0, 1,0, 1,0, 1,0, 0,0);
        u16* curT = D2T; u16* altT = D1T;
        for (int k = 10; k >= 2; --k) {
            cgemm<0><<<grid, 256, 0, stream>>>(BmN, curT, nullptr, altT, BmN, nullptr,
                1.0f/(float)k, 1.0f/(float)k, 0.f, 1,0, 1,0, 1,0, 1,0, 0,0);
            u16* tmp = curT; curT = altT; altT = tmp;
        }
        // k=1: dual write (squarings need N+T)
        cgemm<0><<<grid, 256, 0, stream>>>(BmN, curT, D2N, D2T, BmN, nullptr,
            1.f, 1.f, 0.f, 1,0, 1,0, 1,0, 1,0, 0,0);
        // squarings: E' = E@E + 2E
        u16 *cN = D2N, *cT = D2T, *aN = D1N, *aT = D1T;
        for (int q = 0; q < 6; ++q) {
            const bool last = (q == 5);
            cgemm<0><<<grid, 256, 0, stream>>>(cN, cT,
                last ? P : aN, last ? nullptr : aT,
                cN, nullptr, 1.f, 2.f, 0.f,
                1,0, 1,0, 1, last ? ts0 : 0, 1,0, 0,0);
            u16* t1 = cN; cN = aN; aN = t1;
            u16* t2 = cT; cT = aT; aT = t2;
        }
    }

    // ---- product tree in deviation form: E' = Ea@Eb + Ea + Eb ----
    u16* TA  = CB;       // 64 slots (chunk buffers dead now)
    u16* src = P;
    u16* dst = TA;
    int n = NTS;
    while (n > 1) {
        cgemm<1><<<dim3(4, 4, n/2), 256, 0, stream>>>(
            src, src, dst, nullptr, src, src,
            1.f, 1.f, 1.f, 2,1, 2,0, 1,0, 2,1, 2,0);
        u16* ns = dst;
        dst = (dst == TA) ? P : TA;
        src = ns;
        n >>= 1;
    }

    final_kernel<<<1, 256, 0, stream>>>(src, s0r, s0i, tgr, tgi,
                                        (float*)d_out, out_size);
}

// Round 3
// 344.635 us; speedup vs baseline: 11.9768x; 3.1628x over previous
//
#include <hip/hip_runtime.h>
#include <math.h>

#define DD    256
#define PLQ   65536           // plane elems (u16) = 256*256
#define SLOTB 131072          // complex slot elems (u16): re plane + im plane
#define NTS   128
#define DT_C  0.02f

typedef unsigned short u16;
typedef unsigned int   u32;
typedef __attribute__((ext_vector_type(8))) short s16x8;
typedef __attribute__((ext_vector_type(4))) float f32x4;

typedef __attribute__((address_space(1))) const unsigned int GU32;
typedef __attribute__((address_space(3))) unsigned int LU32;

__device__ __forceinline__ u32 swz(u32 off) {       // 16B-chunk XOR swizzle (involution)
    return off ^ (((off >> 7) & 3u) << 4);
}
__device__ __forceinline__ u16 f2bf(float f) {
    u32 u = __float_as_uint(f);
    return (u16)((u + 0x7FFFu + ((u >> 16) & 1u)) >> 16);
}
__device__ __forceinline__ float bf2f(u16 h) {
    return __uint_as_float(((u32)h) << 16);
}
__device__ __forceinline__ void gll16(const u16* g, char* ldsBase, u32 ldsByteOff) {
    u32 off = (u32)__builtin_amdgcn_readfirstlane((int)ldsByteOff);
    __builtin_amdgcn_global_load_lds((GU32*)g, (LU32*)(ldsBase + off), 16, 0, 0);
}

// ---------------------------------------------------------------------------
// build: X = DT * A_ts  (bf16, N-layout). No scaling/squaring needed:
// ||X|| ~ 0.15-0.3, so degree-6 Taylor error < 4e-8 << bf16 noise.
// ---------------------------------------------------------------------------
__global__ __launch_bounds__(256)
void build_kernel(const float* __restrict__ cr, const float* __restrict__ ci,
                  const float* __restrict__ dre, const float* __restrict__ dimg,
                  const float* __restrict__ gre, const float* __restrict__ gim,
                  u16* __restrict__ Xn, int ts0)
{
    const int ts  = blockIdx.y;
    const int k   = ts0 + ts;
    const int idx = blockIdx.x * 256 + threadIdx.x;

    const float c0 = cr[2*k], c1 = cr[2*k+1];
    const float e0 = ci[2*k], e1 = ci[2*k+1];

    const float gr00 = gre[0*PLQ + idx], gr01 = gre[1*PLQ + idx];
    const float gr10 = gre[2*PLQ + idx], gr11 = gre[3*PLQ + idx];
    const float gi00 = gim[0*PLQ + idx], gi01 = gim[1*PLQ + idx];
    const float gi10 = gim[2*PLQ + idx], gi11 = gim[3*PLQ + idx];

    const float are = dre[idx]  + c0*(gr00+gr01) + c1*(gr10+gr11)
                                - e0*(gi00-gi01) - e1*(gi10-gi11);
    const float aim = dimg[idx] + c0*(gi00+gi01) + c1*(gi10+gi11)
                                + e0*(gr00-gr01) + e1*(gr10-gr11);

    u16* X = Xn + (size_t)ts * SLOTB;
    X[idx]       = f2bf(DT_C * are);
    X[PLQ + idx] = f2bf(DT_C * aim);
}

// ---------------------------------------------------------------------------
// Batched complex bf16 MFMA GEMM with generalized epilogue:
//   acc = A@B  (complex)
//   N-write: vN = aN*acc + bN1*X1 + bN2*X2    (row-major)
//   T-write: vT = aT*acc + bT1*X1 + bT2*X2    (col-major)
// A read from N-layout. B: TRB=0 -> T-layout global via global_load_lds;
// TRB=1 -> N-layout global, scatter-transposed into LDS.
// Tile 64x64, 4 waves, BK=32, mfma_f32_16x16x32_bf16. XCD-swizzled grid.
// ---------------------------------------------------------------------------
template<int TRB>
__global__ __launch_bounds__(256)
void cgemm(const u16* __restrict__ Ab, const u16* __restrict__ Bb,
           u16* __restrict__ outN, u16* __restrict__ outT,
           const u16* __restrict__ X1b, const u16* __restrict__ X2b,
           float aN, float bN1, float bN2,
           float aT, float bT1, float bT2,
           int aS, int aO, int bS, int bO, int cS, int cO,
           int x1S, int x1O, int x2S, int x2O)
{
    __shared__ char lds[16384];   // Are[64][32] | Aim | Bre[64][32](n-major) | Bim

    // ---- bijective XCD-chunked block swizzle (gridDim = 4,4,nz; nwg%8==0) ----
    const u32 nwg = (u32)(gridDim.x * gridDim.y * gridDim.z);
    u32 wg = (u32)blockIdx.x + 4u * (u32)blockIdx.y + 16u * (u32)blockIdx.z;
    u32 w  = wg;
    if ((nwg & 7u) == 0u) { const u32 q = nwg >> 3; w = (wg & 7u) * q + (wg >> 3); }
    const int bn = (int)(w & 3u) * 64;
    const int bm = (int)((w >> 2) & 3u) * 64;
    const int z  = (int)(w >> 4);

    const u16* __restrict__ A = Ab + (size_t)(z*aS + aO) * SLOTB;
    const u16* __restrict__ B = Bb + (size_t)(z*bS + bO) * SLOTB;

    const int t  = threadIdx.x;

    // fast-path staging source mapping: dest chunk D=t*16 -> logical L=swz(D)
    const u32 D  = (u32)t * 16u;
    const u32 L  = swz(D);
    const int sr = (int)(L >> 6);          // tile row 0..63
    const int sk = (int)((L & 63u) >> 1);  // k elem offset 0..31 (16B aligned)
    const u32 wvoff = ((u32)(t >> 6)) * 1024u;  // wave-uniform LDS base

    // TRB staging mapping
    const int kRow = t >> 3;               // 0..31
    const int nCh  = t & 7;                // 0..7 -> n0 = nCh*8

    const int wv = t >> 6, ln = t & 63;
    const int wr = wv >> 1, wc = wv & 1;   // wave tile origin (wr*32, wc*32)
    const int lg = ln >> 4, lc = ln & 15;  // k-group, col

    f32x4 accR[2][2], accI[2][2];
    #pragma unroll
    for (int i = 0; i < 2; ++i)
        #pragma unroll
        for (int j = 0; j < 2; ++j) {
            accR[i][j] = (f32x4){0.f,0.f,0.f,0.f};
            accI[i][j] = (f32x4){0.f,0.f,0.f,0.f};
        }

    for (int k0 = 0; k0 < DD; k0 += 32) {
        __syncthreads();
        // ---- stage A (always gll from N-layout) ----
        gll16(A +        (size_t)(bm + sr)*DD + k0 + sk, lds,     0u + wvoff);
        gll16(A + PLQ +  (size_t)(bm + sr)*DD + k0 + sk, lds,  4096u + wvoff);
        if (TRB == 0) {
            // ---- stage B from T-layout ----
            gll16(B +       (size_t)(bn + sr)*DD + k0 + sk, lds,  8192u + wvoff);
            gll16(B + PLQ + (size_t)(bn + sr)*DD + k0 + sk, lds, 12288u + wvoff);
        } else {
            // ---- stage B from N-layout [k][n]: scatter-transpose ----
            const s16x8 vr = *(const s16x8*)(B +       (size_t)(k0 + kRow)*DD + bn + nCh*8);
            const s16x8 vi = *(const s16x8*)(B + PLQ + (size_t)(k0 + kRow)*DD + bn + nCh*8);
            #pragma unroll
            for (int e = 0; e < 8; ++e) {
                const u32 off = swz((u32)(nCh*8 + e)*64u + (u32)kRow*2u);
                *(u16*)(lds +  8192 + off) = (u16)vr[e];
                *(u16*)(lds + 12288 + off) = (u16)vi[e];
            }
        }
        __syncthreads();

        // ---- fragments ----
        s16x8 ar[2], ai[2], aiN[2], br[2], bi[2];
        #pragma unroll
        for (int fm = 0; fm < 2; ++fm) {
            const u32 so = swz((u32)(wr*32 + fm*16 + lc)*64u + (u32)lg*16u);
            ar[fm]  = *(const s16x8*)(lds + so);
            ai[fm]  = *(const s16x8*)(lds + 4096 + so);
            aiN[fm] = ai[fm] ^ (short)0x8000u;       // negated imag
        }
        #pragma unroll
        for (int fn = 0; fn < 2; ++fn) {
            const u32 so = swz((u32)(wc*32 + fn*16 + lc)*64u + (u32)lg*16u);
            br[fn] = *(const s16x8*)(lds +  8192 + so);
            bi[fn] = *(const s16x8*)(lds + 12288 + so);
        }
        // ---- MFMA ----
        #pragma unroll
        for (int fm = 0; fm < 2; ++fm)
            #pragma unroll
            for (int fn = 0; fn < 2; ++fn) {
                accR[fm][fn] = __builtin_amdgcn_mfma_f32_16x16x32_bf16(ar[fm],  br[fn], accR[fm][fn], 0, 0, 0);
                accR[fm][fn] = __builtin_amdgcn_mfma_f32_16x16x32_bf16(aiN[fm], bi[fn], accR[fm][fn], 0, 0, 0);
                accI[fm][fn] = __builtin_amdgcn_mfma_f32_16x16x32_bf16(ar[fm],  bi[fn], accI[fm][fn], 0, 0, 0);
                accI[fm][fn] = __builtin_amdgcn_mfma_f32_16x16x32_bf16(ai[fm],  br[fn], accI[fm][fn], 0, 0, 0);
            }
    }

    // ---- epilogue: vN/vT combos ----
    u16* oN = outN ? outN + (size_t)(z*cS + cO) * SLOTB : nullptr;
    u16* oT = outT ? outT + (size_t)(z*cS + cO) * SLOTB : nullptr;
    const u16* x1 = X1b ? X1b + (size_t)(z*x1S + x1O) * SLOTB : nullptr;
    const u16* x2 = X2b ? X2b + (size_t)(z*x2S + x2O) * SLOTB : nullptr;

    #pragma unroll
    for (int fm = 0; fm < 2; ++fm)
        #pragma unroll
        for (int fn = 0; fn < 2; ++fn) {
            const int rb = bm + wr*32 + fm*16 + lg*4;
            const int c  = bn + wc*32 + fn*16 + lc;
            u16 tR[4], tI[4];
            #pragma unroll
            for (int j = 0; j < 4; ++j) {
                const int r = rb + j;
                float x1r = 0.f, x1i = 0.f, x2r = 0.f, x2i = 0.f;
                if (x1) { x1r = bf2f(x1[(size_t)r*DD + c]);
                          x1i = bf2f(x1[PLQ + (size_t)r*DD + c]); }
                if (x2) { x2r = bf2f(x2[(size_t)r*DD + c]);
                          x2i = bf2f(x2[PLQ + (size_t)r*DD + c]); }
                if (oN) {
                    const float vR = aN * accR[fm][fn][j] + bN1 * x1r + bN2 * x2r;
                    const float vI = aN * accI[fm][fn][j] + bN1 * x1i + bN2 * x2i;
                    oN[(size_t)r*DD + c]       = f2bf(vR);
                    oN[PLQ + (size_t)r*DD + c] = f2bf(vI);
                }
                const float wR = aT * accR[fm][fn][j] + bT1 * x1r + bT2 * x2r;
                const float wI = aT * accI[fm][fn][j] + bT1 * x1i + bT2 * x2i;
                tR[j] = f2bf(wR); tI[j] = f2bf(wI);
            }
            if (oT) {
                *(ushort4*)(oT + (size_t)c*DD + rb)       = make_ushort4(tR[0], tR[1], tR[2], tR[3]);
                *(ushort4*)(oT + PLQ + (size_t)c*DD + rb) = make_ushort4(tI[0], tI[1], tI[2], tI[3]);
            }
        }
}

// ---------------------------------------------------------------------------
// final: v = s0 + Etot@s0 ; c = sum(v[diag]) ; sT = v/c ; fid = ||sT-tgt||_F
// ---------------------------------------------------------------------------
__global__ __launch_bounds__(256)
void final_kernel(const u16* __restrict__ Et,
                  const float* __restrict__ s0r, const float* __restrict__ s0i,
                  const float* __restrict__ tgr, const float* __restrict__ tgi,
                  float* __restrict__ out, int outSize)
{
    __shared__ float sr[DD], si[DD], vr[DD], vi[DD], red[DD];
    __shared__ float cR, cI;
    const int t = threadIdx.x;
    sr[t] = s0r[t];
    si[t] = s0i[t];
    __syncthreads();

    const u16* Er = Et;
    const u16* Ei = Et + PLQ;
    float ar = sr[t], ai = si[t];
    for (int k = 0; k < DD; ++k) {
        const float pr = bf2f(Er[(size_t)t*DD + k]);
        const float pi = bf2f(Ei[(size_t)t*DD + k]);
        ar += pr*sr[k] - pi*si[k];
        ai += pr*si[k] + pi*sr[k];
    }
    vr[t] = ar; vi[t] = ai;
    __syncthreads();

    if (t == 0) {
        float xr = 0.f, xi = 0.f;
        for (int i = 0; i < 16; ++i) { xr += vr[i*17]; xi += vi[i*17]; }
        cR = xr; cI = xi;
    }
    __syncthreads();

    const float den = cR*cR + cI*cI;
    const float str = (ar*cR + ai*cI) / den;
    const float sti = (ai*cR - ar*cI) / den;

    const float dr = str - tgr[t];
    const float di = sti - tgi[t];
    red[t] = dr*dr + di*di;
    __syncthreads();
    for (int s = 128; s > 0; s >>= 1) {
        if (t < s) red[t] += red[t + s];
        __syncthreads();
    }
    const float fid = sqrtf(red[0]);

    if (outSize >= 2*DD + 1) {
        out[2*t] = str; out[2*t+1] = sti;
        if (t == 0) out[2*DD] = fid;
    } else if (outSize == 2*DD) {
        out[2*t] = str; out[2*t+1] = sti;
    } else {
        out[t] = str;
        if (t == 0 && outSize > DD) out[DD] = fid;
    }
}

// ---------------------------------------------------------------------------
extern "C" void kernel_launch(void* const* d_in, const int* in_sizes, int n_in,
                              void* d_out, int out_size, void* d_ws, size_t ws_size,
                              hipStream_t stream)
{
    (void)in_sizes; (void)n_in;
    const float* cr   = (const float*)d_in[0];
    const float* ci   = (const float*)d_in[1];
    const float* dre  = (const float*)d_in[2];
    const float* dimg = (const float*)d_in[3];
    const float* gre  = (const float*)d_in[4];
    const float* gim  = (const float*)d_in[5];
    const float* s0r  = (const float*)d_in[6];
    const float* s0i  = (const float*)d_in[7];
    const float* tgr  = (const float*)d_in[8];
    const float* tgi  = (const float*)d_in[9];

    // Taylor-6 coefficients 1/k!
    const float c1 = 1.f, c2 = 0.5f, c3 = 1.f/6.f,
                c4 = 1.f/24.f, c5 = 1.f/120.f, c6 = 1.f/720.f;

    u16* ws = (u16*)d_ws;
    u16* P  = ws;                          // 128 N-slots: expm deviations E_ts
    u16* CB = ws + 128L * SLOTB;           // chunk region (also tree ping buffer)

    long availU = (long)(ws_size / 2) - 128L * SLOTB;
    int C = (int)(availU / (4L * SLOTB));
    if (C > NTS) C = NTS;
    if (C < 16) C = 16;                    // tree ping (64 slots) must fit in 4C

    for (int ts0 = 0; ts0 < NTS; ts0 += C) {
        int nb = NTS - ts0; if (nb > C) nb = C;
        u16* Xn  = CB;
        u16* P2  = CB + 1L*C*SLOTB;
        u16* L3T = CB + 2L*C*SLOTB;
        u16* MT  = CB + 3L*C*SLOTB;

        build_kernel<<<dim3(PLQ/256, nb), 256, 0, stream>>>(
            cr, ci, dre, dimg, gre, gim, Xn, ts0);

        const dim3 grid(4, 4, nb);
        // G1: P2 = X@X ; L3T = c6*P2 + c5*X  (T layout)
        cgemm<1><<<grid, 256, 0, stream>>>(Xn, Xn, P2, L3T, Xn, nullptr,
            1.f, 0.f, 0.f,  c6, c5, 0.f,
            1,0, 1,0, 1,0, 1,0, 0,0);
        // G2: MT = P2@L3T + c3*X + c4*P2  (T layout)
        cgemm<0><<<grid, 256, 0, stream>>>(P2, L3T, nullptr, MT, Xn, P2,
            0.f, 0.f, 0.f,  1.f, c3, c4,
            1,0, 1,0, 1,0, 1,0, 1,0);
        // G3: E = P2@MT + c1*X + c2*P2  -> P[ts0+z]  (N layout)
        cgemm<0><<<grid, 256, 0, stream>>>(P2, MT, P, nullptr, Xn, P2,
            1.f, c1, c2,  0.f, 0.f, 0.f,
            1,0, 1,0, 1,ts0, 1,0, 1,0);
    }

    // ---- product tree in deviation form: E' = Ea@Eb + Ea + Eb ----
    u16* TA  = CB;       // 64 slots (chunk buffers dead now)
    u16* src = P;
    u16* dst = TA;
    int n = NTS;
    while (n > 1) {
        cgemm<1><<<dim3(4, 4, n/2), 256, 0, stream>>>(
            src, src, dst, nullptr, src, src,
            1.f, 1.f, 1.f,  0.f, 0.f, 0.f,
            2,1, 2,0, 1,0, 2,1, 2,0);
        u16* ns = dst;
        dst = (dst == TA) ? P : TA;
        src = ns;
        n >>= 1;
    }

    final_kernel<<<1, 256, 0, stream>>>(src, s0r, s0i, tgr, tgi,
                                        (float*)d_out, out_size);
}